// Round 16
// baseline (119.312 us; speedup 1.0000x reference)
//
#include <hip/hip_runtime.h>
#include <cstdint>

// CIN chain: B=1024, F0=32, EMB=64, layers 128/128/128.
// cur[b,k,e] = sum_{i,j} x[b,i,e]*h[b,j,e]*W[i*fi+j,k]
//
// R28: UNION OF BEST = R21 skeleton (single-pass 24 KB exchange, 5
// barriers) x R27 j-major kloop. Session plateau 114.6-118.4 over
// R20b/R21/R23b/R27; R21 (114.6) is best with single-pass exchange,
// R27 (117.5) has the leaner kloop but paid 2 extra barriers/phase
// for the 2-pass exchange. Merge keeps both wins:
//  * kloop (R27): Wt'[c=j][m][kk=i] j-major; B-frag = xF (4 regs,
//    loaded once per block) * broadcast(h[c][e] scalar, 4 ds_read_u16
//    per chunk). No hv b128 reads, no sX, no hT image. mt=4 (all 64
//    hidden rows), wave w = j-quarter c0=w*NCH/4, 2-slot dist-1 af
//    prefetch, setprio on MFMA cluster.
//  * exchange (R20b/R21): single-pass 12-slot f16 XC (24 KB); wave w
//    writes its 3 non-owned mt blocks, reads 3 partials for mt=w,
//    epilogues rows w*16.. into hB (hJ only). One barrier pair/phase.
//  * sgemm (R27): S' j-major [b][j*32+i], half4 vector stores; direct
//    dot unchanged (Wt' rows share the permutation — R25/R27 verified).
// LDS 38912 B: xT 5120 | hB 9216 | XC 24576. Grid 1024, 256 thr,
// (256,2) bounds everywhere ((256,4) = 64-VGPR spill trap R16/R18/R22).
//   hB: xJ(p72) -> [B1] -> hJ1 -> [B3] -> hJ2   (rows j, cols e)
//   xT: [e][i] p40, whole kernel (xF source)

typedef _Float16 half8  __attribute__((ext_vector_type(8)));
typedef _Float16 half4_ __attribute__((ext_vector_type(4)));
typedef _Float16 half2_ __attribute__((ext_vector_type(2)));
typedef float    f32x4  __attribute__((ext_vector_type(4)));

// Pack W (fan_in,128) f32 -> j-major chunked f16:
// Wt'[c][m][kk] = W[kk*fi + c][m];  fi=32 (L0) / 64 (L1,L2).
__global__ void pack_w_all(const float* __restrict__ W0, _Float16* __restrict__ Wt0,
                           const float* __restrict__ W1, _Float16* __restrict__ Wt1,
                           const float* __restrict__ W2, _Float16* __restrict__ Wt2)
{
    __shared__ _Float16 ldsT[128 * 33];
    const int blk = blockIdx.x, t = threadIdx.x;
    const float* W;
    _Float16* Wt;
    int c, fi;
    if (blk < 32)       { W = W0; Wt = Wt0; c = blk;      fi = 32; }
    else if (blk < 96)  { W = W1; Wt = Wt1; c = blk - 32; fi = 64; }
    else                { W = W2; Wt = Wt2; c = blk - 96; fi = 64; }

    for (int p = t; p < 32 * 128; p += 256) {
        int kk = p >> 7, m = p & 127;
        ldsT[m * 33 + kk] = (_Float16)W[(size_t)(kk * fi + c) * 128 + m];
    }
    __syncthreads();
    int m = t >> 1, kk0 = (t & 1) * 16;
    half8 v0, v1;
#pragma unroll
    for (int i = 0; i < 8; ++i) {
        v0[i] = ldsT[m * 33 + kk0 + i];
        v1[i] = ldsT[m * 33 + kk0 + 8 + i];
    }
    *(half8*)(Wt + (size_t)c * 4096 + t * 16)     = v0;
    *(half8*)(Wt + (size_t)c * 4096 + t * 16 + 8) = v1;
}

// kloop: all 64 hidden rows (mt=4), this wave's j-QUARTER.
// af from Wt' (global, 2-slot dist-1); B-frag = xF[nt] * broadcast of
// h scalar hB[c*72 + nt*16 + lr]. setprio around MFMA cluster.
template<int NCH>
__device__ __forceinline__ void kloop_t(f32x4 (&acc)[4][4],
    const _Float16* __restrict__ WtL, const _Float16* __restrict__ hB,
    const half8 (&xF)[4], int lr, int q, int w)
{
#pragma unroll
    for (int mt = 0; mt < 4; ++mt)
#pragma unroll
        for (int nt = 0; nt < 4; ++nt)
            acc[mt][nt] = f32x4{0.0f, 0.0f, 0.0f, 0.0f};

    constexpr int HC = NCH / 4;               // chunks (j's) per wave
    const int c0 = w * HC;
    const _Float16* aG = WtL + (size_t)c0 * 4096 + lr * 32 + q * 8;
    const _Float16* hP = hB + (size_t)c0 * 72 + lr;

    half8 afA[4], afB[4];
    _Float16 xsA[4], xsB[4];

    auto pf = [&](half8* af, _Float16* xs, int cc) {
        const _Float16* ag = aG + (size_t)cc * 4096;
#pragma unroll
        for (int mt = 0; mt < 4; ++mt)
            af[mt] = *(const half8*)(ag + mt * 512);
        const _Float16* hh = hP + cc * 72;
#pragma unroll
        for (int nt = 0; nt < 4; ++nt)
            xs[nt] = hh[nt * 16];
    };
    auto cp = [&](half8* af, _Float16* xs) {
        __builtin_amdgcn_s_setprio(1);
#pragma unroll
        for (int nt = 0; nt < 4; ++nt) {
            half2_ xv2 = {xs[nt], xs[nt]};
            half8 xv8 = __builtin_shufflevector(xv2, xv2, 0, 1, 0, 1, 0, 1, 0, 1);
            half8 bf = xF[nt] * xv8;
#pragma unroll
            for (int mt = 0; mt < 4; ++mt)
                acc[mt][nt] = __builtin_amdgcn_mfma_f32_16x16x32_f16(
                    af[mt], bf, acc[mt][nt], 0, 0, 0);
        }
        __builtin_amdgcn_s_setprio(0);
    };

    pf(afA, xsA, 0);
    for (int cc = 0; cc < HC; cc += 2) {
        pf(afB, xsB, cc + 1);
        cp(afA, xsA);
        if (cc + 2 < HC) pf(afA, xsA, cc + 2);
        cp(afB, xsB);
    }
}

// Fused kernel. Block = 1 batch, 256 thr = 4 waves (j-quarter w).
__global__ __launch_bounds__(256, 2)
void cin_fused(const float* __restrict__ x,          // (1024,32,64) f32
               const _Float16* __restrict__ Wt0,
               const _Float16* __restrict__ Wt1,
               const float* __restrict__ bs0,
               const float* __restrict__ bs1,
               _Float16* __restrict__ S0,             // (1024,1024) j-major
               _Float16* __restrict__ S1,             // (1024,2048) j-major
               _Float16* __restrict__ S2)             // (1024,2048) j-major
{
    __shared__ alignas(16) char smem[38912];
    _Float16* xT   = (_Float16*)smem;                  // 5120 B  [e][i] p40
    _Float16* hB   = (_Float16*)(smem + 5120);         // 9216 B  [j][e] p72
    _Float16* XC16 = (_Float16*)(smem + 14336);        // 24576 B exchange

    const int t = threadIdx.x, lane = t & 63, w = t >> 6;
    const int lr = lane & 15, q = lane >> 4;
    const int b = blockIdx.x;

    // prologue: x -> hB (xJ, p72) + xT ([e][i], p40)
    {
        const float4* xv = (const float4*)(x + (size_t)b * 2048);
#pragma unroll
        for (int s = 0; s < 2; ++s) {
            int p4 = t + s * 256;
            float4 v = xv[p4];
            int idx = p4 * 4, i = idx >> 6, e0 = idx & 63;
            _Float16 h0 = (_Float16)v.x, h1 = (_Float16)v.y;
            _Float16 h2 = (_Float16)v.z, h3 = (_Float16)v.w;
            half4_ pk = {h0, h1, h2, h3};
            *(half4_*)(hB + i * 72 + e0) = pk;
            xT[(e0 + 0) * 40 + i] = h0;
            xT[(e0 + 1) * 40 + i] = h1;
            xT[(e0 + 2) * 40 + i] = h2;
            xT[(e0 + 3) * 40 + i] = h3;
        }
    }
    __syncthreads();                                   // B0

    // persistent fragments: xF (kloop B-source, whole kernel);
    // aF pair (sgemm A, it = w&1 folds into the load ADDRESS)
    half8 xF[4];
#pragma unroll
    for (int nt = 0; nt < 4; ++nt)
        xF[nt] = *(const half8*)(xT + (nt * 16 + lr) * 40 + q * 8);
    const int it = w & 1;
    const half8 aF0 = *(const half8*)(hB + (it * 16 + lr) * 72 + q * 8);
    const half8 aF1 = *(const half8*)(hB + (it * 16 + lr) * 72 + q * 8 + 32);

    f32x4 acc[4][4];

    // single-pass 4-way exchange: wave w writes its 3 non-owned mt
    // blocks; slot(tgt mt, writer w) = mt*3 + (w>mt ? w-1 : w).
    auto xchg_write = [&]() {
#pragma unroll
        for (int mt = 0; mt < 4; ++mt) {
            if (mt == w) continue;                     // wave-uniform
            const int slot = mt * 3 + (w > mt ? w - 1 : w);
#pragma unroll
            for (int cc = 0; cc < 2; ++cc) {
                half8 hv8;
#pragma unroll
                for (int r = 0; r < 4; ++r) {
                    hv8[r]     = (_Float16)acc[mt][cc * 2][r];
                    hv8[4 + r] = (_Float16)acc[mt][cc * 2 + 1][r];
                }
                *(half8*)(XC16 + slot * 1024 + cc * 512 + lane * 8) = hv8;
            }
        }
    };

    // combine partials into aw (static ref) + epilogue of 16 rows (hJ)
    auto finish = [&](f32x4 (&aw)[4], const float* bs) {
#pragma unroll
        for (int p = 0; p < 3; ++p) {
#pragma unroll
            for (int cc = 0; cc < 2; ++cc) {
                half8 hv8 = *(const half8*)(XC16 + (w * 3 + p) * 1024
                                            + cc * 512 + lane * 8);
#pragma unroll
                for (int r = 0; r < 4; ++r) {
                    aw[cc * 2][r]     += (float)hv8[r];
                    aw[cc * 2 + 1][r] += (float)hv8[4 + r];
                }
            }
        }
        const int jb = w * 16 + q * 4;
        const float b0f = bs[jb + 0], b1f = bs[jb + 1];
        const float b2f = bs[jb + 2], b3f = bs[jb + 3];
#pragma unroll
        for (int nt = 0; nt < 4; ++nt) {
            const int e = nt * 16 + lr;
            hB[(jb + 0) * 72 + e] = (_Float16)(aw[nt][0] + b0f);
            hB[(jb + 1) * 72 + e] = (_Float16)(aw[nt][1] + b1f);
            hB[(jb + 2) * 72 + e] = (_Float16)(aw[nt][2] + b2f);
            hB[(jb + 3) * 72 + e] = (_Float16)(aw[nt][3] + b3f);
        }
    };
    auto combine_epi = [&](const float* bs) {
        if (w == 0)      finish(acc[0], bs);
        else if (w == 1) finish(acc[1], bs);
        else if (w == 2) finish(acc[2], bs);
        else             finish(acc[3], bs);
    };

    // S'_l[b][j*32+i] = sum_e x[i,e]*h[j,e]; tiles split across waves,
    // i-tile = it (aF), jt varies; j-major half4 vector stores.
    auto sgemm = [&](int fi, _Float16* Sdst) {
        const int nT = fi >> 3;                        // 4 or 8 tiles
        _Float16* Sb = Sdst + (size_t)b * (32 * fi);
        for (int tt = w; tt < nT; tt += 4) {
            const int jt = tt >> 1;
            f32x4 sa = {0.0f, 0.0f, 0.0f, 0.0f};
            half8 bv0 = *(const half8*)(hB + (jt * 16 + lr) * 72 + q * 8);
            half8 bv1 = *(const half8*)(hB + (jt * 16 + lr) * 72 + q * 8 + 32);
            sa = __builtin_amdgcn_mfma_f32_16x16x32_f16(aF0, bv0, sa, 0, 0, 0);
            sa = __builtin_amdgcn_mfma_f32_16x16x32_f16(aF1, bv1, sa, 0, 0, 0);
            half4_ v0;
#pragma unroll
            for (int r = 0; r < 4; ++r) v0[r] = (_Float16)sa[r];
            *(half4_*)(Sb + (jt * 16 + lr) * 32 + it * 16 + q * 4) = v0;
        }
    };

    // ---- phase 0 ----  (hB = xJ; kloop chunk c = j of x)
    sgemm(32, S0);                            // S0' = j-major x @ x^T
    kloop_t<32>(acc, Wt0, hB, xF, lr, q, w);
    xchg_write();
    __syncthreads();                          // B1
    combine_epi(bs0);                         // hB := h1
    __syncthreads();                          // B2
    // ---- phase 1 ----
    sgemm(64, S1);                            // S1' = j-major x @ h1^T
    kloop_t<64>(acc, Wt1, hB, xF, lr, q, w);
    xchg_write();
    __syncthreads();                          // B3
    combine_epi(bs1);                         // hB := h2
    __syncthreads();                          // B4
    sgemm(64, S2);                            // S2' = j-major x @ h2^T
}

// Direct-output GEMM: out[b, ob+k] = S'_l[b,:] . Wt'_l[:, dm0+k] + 64*bias.
// (S' and Wt' share the j-major permutation -> dot unchanged.)
// 1024 tasks, 1 task/block, 4-way K-split across waves; wave 0 combines.
__global__ __launch_bounds__(256, 2)
void cin_direct(const _Float16* __restrict__ S0v, const _Float16* __restrict__ S1v,
                const _Float16* __restrict__ S2v,
                const _Float16* __restrict__ Wt0, const _Float16* __restrict__ Wt1,
                const _Float16* __restrict__ Wt2,
                const float* __restrict__ bs0, const float* __restrict__ bs1,
                const float* __restrict__ bs2,
                float* __restrict__ out)
{
    __shared__ f32x4 red[3][64];
    const int t = threadIdx.x, lane = t & 63, kh = t >> 6;
    const int lr = lane & 15, q = lane >> 4;
    const int task = blockIdx.x;

    const _Float16 *S, *Wt;
    const float* bias;
    int fan, nch, dm0, ob, idx;
    if (task < 256)      { S = S0v; Wt = Wt0; bias = bs0; fan = 1024; nch = 32; dm0 = 64; ob = 0;   idx = task; }
    else if (task < 512) { S = S1v; Wt = Wt1; bias = bs1; fan = 2048; nch = 64; dm0 = 64; ob = 64;  idx = task - 256; }
    else                 { S = S2v; Wt = Wt2; bias = bs2; fan = 2048; nch = 64; dm0 = 0;  ob = 128; idx = task - 512; }
    const int bt = idx & 63, kt = idx >> 6;
    const int bbase = bt * 16;
    const int hq = nch >> 2, c0 = kh * hq;

    const _Float16* aG = Wt + (size_t)(dm0 + kt * 16 + lr) * 32 + q * 8
                            + (size_t)c0 * 4096;
    const _Float16* bG = S + (size_t)(bbase + lr) * fan + q * 8 + c0 * 32;

    f32x4 acc = {0.0f, 0.0f, 0.0f, 0.0f};
    half8 aA = *(const half8*)(aG);
    half8 bA = *(const half8*)(bG);
    for (int c = 0; c < hq; c += 2) {
        half8 aB = *(const half8*)(aG + (size_t)(c + 1) * 4096);
        half8 bB = *(const half8*)(bG + (c + 1) * 32);
        acc = __builtin_amdgcn_mfma_f32_16x16x32_f16(aA, bA, acc, 0, 0, 0);
        if (c + 2 < hq) {
            aA = *(const half8*)(aG + (size_t)(c + 2) * 4096);
            bA = *(const half8*)(bG + (c + 2) * 32);
        }
        acc = __builtin_amdgcn_mfma_f32_16x16x32_f16(aB, bB, acc, 0, 0, 0);
    }
    if (kh != 0) red[kh - 1][lane] = acc;
    __syncthreads();
    if (kh == 0) {
#pragma unroll
        for (int p = 0; p < 3; ++p) {
            f32x4 o = red[p][lane];
#pragma unroll
            for (int r = 0; r < 4; ++r) acc[r] += o[r];
        }
#pragma unroll
        for (int r = 0; r < 4; ++r) {
            int kl = kt * 16 + q * 4 + r;
            out[(size_t)(bbase + lr) * 256 + ob + kl]
                = acc[r] + 64.0f * bias[dm0 + kl];
        }
    }
}

extern "C" void kernel_launch(void* const* d_in, const int* in_sizes, int n_in,
                              void* d_out, int out_size, void* d_ws, size_t ws_size,
                              hipStream_t stream)
{
    const float* x  = (const float*)d_in[0];
    const float* W0 = (const float*)d_in[1];
    const float* b0 = (const float*)d_in[2];
    const float* W1 = (const float*)d_in[3];
    const float* b1 = (const float*)d_in[4];
    const float* W2 = (const float*)d_in[5];
    const float* b2 = (const float*)d_in[6];
    float* out = (float*)d_out;

    char* ws = (char*)d_ws;
    _Float16* Wt0 = (_Float16*)(ws + 0);           // 256 KB
    _Float16* Wt1 = (_Float16*)(ws + 262144);      // 512 KB
    _Float16* Wt2 = (_Float16*)(ws + 786432);      // 512 KB
    _Float16* S0  = (_Float16*)(ws + 1310720);     // 2 MB  (1024 x 1024 f16)
    _Float16* S1  = (_Float16*)(ws + 3407872);     // 4 MB  (1024 x 2048 f16)
    _Float16* S2  = (_Float16*)(ws + 7602176);     // 4 MB
    (void)in_sizes; (void)n_in; (void)out_size; (void)ws_size;

    hipLaunchKernelGGL(pack_w_all, dim3(160), dim3(256), 0, stream,
                       W0, Wt0, W1, Wt1, W2, Wt2);

    hipLaunchKernelGGL(cin_fused, dim3(1024), dim3(256), 0, stream,
                       x, Wt0, Wt1, b0, b1, S0, S1, S2);

    hipLaunchKernelGGL(cin_direct, dim3(1024), dim3(256), 0, stream,
                       S0, S1, S2, Wt0, Wt1, Wt2, b0, b1, b2, out);
}

// Round 17
// 116.404 us; speedup vs baseline: 1.0250x; 1.0250x over previous
//
#include <hip/hip_runtime.h>
#include <cstdint>

// CIN chain: B=1024, F0=32, EMB=64, layers 128/128/128.
// cur[b,k,e] = sum_{i,j} x[b,i,e]*h[b,j,e]*W[i*fi+j,k]
//
// R29: REVERT TO BEST-MEASURED (R21, 114.6 us). Session post-mortem:
// seven structural attacks on cin_fused (occupancy 8->24 waves/CU,
// prefetch depth, barrier count 8->6->0 via j-major algebra, exchange
// width, VALU elimination, cooperative fusion) all land in the
// 114.6-125.6 band; R28's visible profile shows the invariant: ~60%
// stall cycles with MfmaUtil 22% / VALU 18% / HBM 4% — a latency+
// barrier floor plus ~43 us of in-window harness fill, not a pipe
// roofline. Measured ranking: R21 114.6 < R20b 115.5 < R27 117.5 <
// R23b 118.4 < R28 119.3. This is R21 byte-for-byte:
//  * cin_fused: 1 batch/block, 256 thr = 4 waves, K-split-4, mt=4
//    kloop (named frags), 4-slot af rotation dist-2, setprio on MFMA,
//    single-pass 24 KB f16 exchange, LDS 47104 (3 blocks/CU), (256,2).
//  * cin_direct: 1 task/block, 4-way K-split, grid 1024, (256,4)
//    (direct's ~30-reg live set fits the 64-VGPR target).
// LDS: sX 4K | R_A 9216 | R_B 9216 | XC 24K  (47104 B)
//   R_A hT0(p40) -> [B1] -> hJ1(p72) -> [B3] -> hJ2(p72)
//   R_B xJ(p72)  -> [B1] -> hT1(p72)

typedef _Float16 half8  __attribute__((ext_vector_type(8)));
typedef _Float16 half4_ __attribute__((ext_vector_type(4)));
typedef _Float16 half2_ __attribute__((ext_vector_type(2)));
typedef float    f32x4  __attribute__((ext_vector_type(4)));

// Pack W (fan_in,128) f32 -> chunked f16 Wt[c][m][kk] = W[c*32+kk][m].
__global__ void pack_w_all(const float* __restrict__ W0, _Float16* __restrict__ Wt0,
                           const float* __restrict__ W1, _Float16* __restrict__ Wt1,
                           const float* __restrict__ W2, _Float16* __restrict__ Wt2)
{
    __shared__ _Float16 ldsT[128 * 33];
    const int blk = blockIdx.x, t = threadIdx.x;
    const float* W;
    _Float16* Wt;
    int c;
    if (blk < 32)       { W = W0; Wt = Wt0; c = blk; }
    else if (blk < 96)  { W = W1; Wt = Wt1; c = blk - 32; }
    else                { W = W2; Wt = Wt2; c = blk - 96; }

    for (int p = t; p < 32 * 128; p += 256) {
        int kk = p >> 7, m = p & 127;
        ldsT[m * 33 + kk] = (_Float16)W[(size_t)(c * 32 + kk) * 128 + m];
    }
    __syncthreads();
    int m = t >> 1, kk0 = (t & 1) * 16;
    half8 v0, v1;
#pragma unroll
    for (int i = 0; i < 8; ++i) {
        v0[i] = ldsT[m * 33 + kk0 + i];
        v1[i] = ldsT[m * 33 + kk0 + 8 + i];
    }
    *(half8*)(Wt + (size_t)c * 4096 + t * 16)     = v0;
    *(half8*)(Wt + (size_t)c * 4096 + t * 16 + 8) = v1;
}

// Templated kloop: ALL 64 hidden rows (mt=4), this wave's K-quarter.
// af: 4-slot rotation, issue distance 2 bodies. hv/xs: 2-slot, dist 1.
template<int NCH, int ISH, int PH>
__device__ __forceinline__ void kloop_t(f32x4 (&acc)[4][4],
    const _Float16* __restrict__ WtL, const _Float16* __restrict__ hb,
    const _Float16* __restrict__ sX, int lr, int q, int w)
{
#pragma unroll
    for (int mt = 0; mt < 4; ++mt)
#pragma unroll
        for (int nt = 0; nt < 4; ++nt)
            acc[mt][nt] = f32x4{0.0f, 0.0f, 0.0f, 0.0f};

    constexpr int HC = NCH / 4;               // chunks per wave (8 or 16)
    const int c0 = w * HC;
    const _Float16* aG = WtL + (size_t)c0 * 4096 + lr * 32 + q * 8;
    const _Float16* hP = hb + lr * PH + q * 8;
    const _Float16* xP = sX + lr;

    half8 afA[4], afB[4], afC[4], afD[4], hvA[4], hvB[4];
    _Float16 xsA[4], xsB[4];

    auto pfa = [&](half8* af, int cc) {
        const _Float16* ag = aG + (size_t)cc * 4096;
#pragma unroll
        for (int mt = 0; mt < 4; ++mt)
            af[mt] = *(const half8*)(ag + mt * 512);
    };
    auto pfh = [&](half8* hv, _Float16* xs, int cc) {
        const int c  = c0 + cc;
        const int i  = c >> ISH;
        const int j0 = (c & ((1 << ISH) - 1)) << 5;
        const _Float16* hh = hP + j0;
        const _Float16* xb = xP + (i << 6);
#pragma unroll
        for (int nt = 0; nt < 4; ++nt) {
            hv[nt] = *(const half8*)(hh + nt * (PH * 16));
            xs[nt] = xb[nt * 16];
        }
    };
    auto cp = [&](half8* af, half8* hv, _Float16* xs) {
        __builtin_amdgcn_s_setprio(1);
#pragma unroll
        for (int nt = 0; nt < 4; ++nt) {
            half2_ xv2 = {xs[nt], xs[nt]};
            half8 xv8 = __builtin_shufflevector(xv2, xv2, 0, 1, 0, 1, 0, 1, 0, 1);
            half8 bf = hv[nt] * xv8;
#pragma unroll
            for (int mt = 0; mt < 4; ++mt)
                acc[mt][nt] = __builtin_amdgcn_mfma_f32_16x16x32_f16(
                    af[mt], bf, acc[mt][nt], 0, 0, 0);
        }
        __builtin_amdgcn_s_setprio(0);
    };

    pfa(afA, 0); pfa(afB, 1);
    pfh(hvA, xsA, 0);
    for (int cc = 0; cc < HC; cc += 4) {
        pfa(afC, cc + 2);
        pfh(hvB, xsB, cc + 1);
        cp(afA, hvA, xsA);                    // body cc
        pfa(afD, cc + 3);
        pfh(hvA, xsA, cc + 2);
        cp(afB, hvB, xsB);                    // body cc+1
        if (cc + 4 < HC) pfa(afA, cc + 4);
        pfh(hvB, xsB, cc + 3);
        cp(afC, hvA, xsA);                    // body cc+2
        if (cc + 5 < HC) pfa(afB, cc + 5);
        if (cc + 4 < HC) pfh(hvA, xsA, cc + 4);
        cp(afD, hvB, xsB);                    // body cc+3
    }
}

// Fused hidden+S kernel. Block = 1 batch, 256 thr = 4 waves (K-quarter w).
__global__ __launch_bounds__(256, 2)
void cin_fused(const float* __restrict__ x,          // (1024,32,64) f32
               const _Float16* __restrict__ Wt0,
               const _Float16* __restrict__ Wt1,
               const float* __restrict__ bs0,
               const float* __restrict__ bs1,
               _Float16* __restrict__ S0,             // (1024,1024)
               _Float16* __restrict__ S1,             // (1024,2048)
               _Float16* __restrict__ S2)             // (1024,2048)
{
    __shared__ alignas(16) char smem[47104];
    _Float16* sX   = (_Float16*)smem;                  // 4 KB  [i*64+e]
    _Float16* R_A  = (_Float16*)(smem + 4096);         // 9216 B
    _Float16* R_B  = (_Float16*)(smem + 13312);        // 9216 B
    _Float16* XC16 = (_Float16*)(smem + 22528);        // 24 KB exchange

    const int t = threadIdx.x, lane = t & 63, w = t >> 6;
    const int lr = lane & 15, q = lane >> 4;
    const int b = blockIdx.x;

    // prologue: x -> sX [i][e]; xJ (pitch 72) -> R_B; hT0 (pitch 40) -> R_A
    {
        const float4* xv = (const float4*)(x + (size_t)b * 2048);
#pragma unroll
        for (int s = 0; s < 2; ++s) {
            int p4 = t + s * 256;
            float4 v = xv[p4];
            int idx = p4 * 4, i = idx >> 6, e0 = idx & 63;
            _Float16 h0 = (_Float16)v.x, h1 = (_Float16)v.y;
            _Float16 h2 = (_Float16)v.z, h3 = (_Float16)v.w;
            half4_ pk = {h0, h1, h2, h3};
            *(half4_*)(sX + i * 64 + e0) = pk;
            *(half4_*)(R_B + i * 72 + e0) = pk;
            R_A[(e0 + 0) * 40 + i] = h0;
            R_A[(e0 + 1) * 40 + i] = h1;
            R_A[(e0 + 2) * 40 + i] = h2;
            R_A[(e0 + 3) * 40 + i] = h3;
        }
    }
    __syncthreads();                                   // B0

    // persistent sgemm A-fragments, NAMED (it = w&1 folds into address)
    const int it = w & 1;
    const half8 aF0 = *(const half8*)(R_B + (it * 16 + lr) * 72 + q * 8);
    const half8 aF1 = *(const half8*)(R_B + (it * 16 + lr) * 72 + q * 8 + 32);

    f32x4 acc[4][4];

    // 4-way exchange: wave w writes its 3 non-owned mt blocks as f16.
    // slot(writer w, mt) = mt*3 + (w>mt ? w-1 : w); reader of mt=w reads
    // slots w*3 .. w*3+2. 12 slots x 1024 f16 = 24 KB.
    auto xchg_write = [&]() {
#pragma unroll
        for (int mt = 0; mt < 4; ++mt) {
            if (mt == w) continue;                     // wave-uniform
            const int slot = mt * 3 + (w > mt ? w - 1 : w);
#pragma unroll
            for (int cc = 0; cc < 2; ++cc) {
                half8 hv8;
#pragma unroll
                for (int r = 0; r < 4; ++r) {
                    hv8[r]     = (_Float16)acc[mt][cc * 2][r];
                    hv8[4 + r] = (_Float16)acc[mt][cc * 2 + 1][r];
                }
                *(half8*)(XC16 + slot * 1024 + cc * 512 + lane * 8) = hv8;
            }
        }
    };

    // combine partials into aw (static ref) + epilogue of 16 rows
    auto finish = [&](f32x4 (&aw)[4], const float* bs,
                      _Float16* hJ, _Float16* hT, bool wantT) {
#pragma unroll
        for (int p = 0; p < 3; ++p) {
#pragma unroll
            for (int cc = 0; cc < 2; ++cc) {
                half8 hv8 = *(const half8*)(XC16 + (w * 3 + p) * 1024
                                            + cc * 512 + lane * 8);
#pragma unroll
                for (int r = 0; r < 4; ++r) {
                    aw[cc * 2][r]     += (float)hv8[r];
                    aw[cc * 2 + 1][r] += (float)hv8[4 + r];
                }
            }
        }
        const int jb = w * 16 + q * 4;
        const float b0f = bs[jb + 0], b1f = bs[jb + 1];
        const float b2f = bs[jb + 2], b3f = bs[jb + 3];
#pragma unroll
        for (int nt = 0; nt < 4; ++nt) {
            const int e = nt * 16 + lr;
            half4_ vh;
            vh[0] = (_Float16)(aw[nt][0] + b0f);
            vh[1] = (_Float16)(aw[nt][1] + b1f);
            vh[2] = (_Float16)(aw[nt][2] + b2f);
            vh[3] = (_Float16)(aw[nt][3] + b3f);
            hJ[(jb + 0) * 72 + e] = vh[0];
            hJ[(jb + 1) * 72 + e] = vh[1];
            hJ[(jb + 2) * 72 + e] = vh[2];
            hJ[(jb + 3) * 72 + e] = vh[3];
            if (wantT) *(half4_*)(hT + e * 72 + jb) = vh;
        }
    };
    auto combine_epi = [&](const float* bs, _Float16* hJ, _Float16* hT,
                           bool wantT) {
        if (w == 0)      finish(acc[0], bs, hJ, hT, wantT);
        else if (w == 1) finish(acc[1], bs, hJ, hT, wantT);
        else if (w == 2) finish(acc[2], bs, hJ, hT, wantT);
        else             finish(acc[3], bs, hJ, hT, wantT);
    };

    // S_l[b][i*fi+j] = sum_e x[i,e]*h[j,e]; tiles split across 4 waves,
    // this wave's i-tile fixed = it (aF0/aF1), jt varies.
    auto sgemm = [&](const _Float16* hJ, int fi, _Float16* Sdst) {
        const int nT = fi >> 3;                        // 4 or 8 tiles
        for (int tt = w; tt < nT; tt += 4) {
            const int jt = tt >> 1;
            f32x4 sa = {0.0f, 0.0f, 0.0f, 0.0f};
            half8 bv0 = *(const half8*)(hJ + (jt * 16 + lr) * 72 + q * 8);
            half8 bv1 = *(const half8*)(hJ + (jt * 16 + lr) * 72 + q * 8 + 32);
            sa = __builtin_amdgcn_mfma_f32_16x16x32_f16(aF0, bv0, sa, 0, 0, 0);
            sa = __builtin_amdgcn_mfma_f32_16x16x32_f16(aF1, bv1, sa, 0, 0, 0);
#pragma unroll
            for (int r = 0; r < 4; ++r)
                Sdst[(size_t)b * (32 * fi) + (it * 16 + q * 4 + r) * fi
                     + jt * 16 + lr] = (_Float16)sa[r];
        }
    };

    // ---- phase 0 ----
    sgemm(R_B, 32, S0);                          // S0 = x @ x^T (B from xJ)
    kloop_t<32, 0, 40>(acc, Wt0, R_A, sX, lr, q, w);
    xchg_write();
    __syncthreads();                             // B1
    combine_epi(bs0, R_A, R_B, true);            // hJ1 -> R_A, hT1 -> R_B
    __syncthreads();                             // B2
    // ---- phase 1 ----
    sgemm(R_A, 64, S1);                          // S1 = x @ h1^T
    kloop_t<64, 1, 72>(acc, Wt1, R_B, sX, lr, q, w);
    xchg_write();
    __syncthreads();                             // B3
    combine_epi(bs1, R_A, nullptr, false);       // hJ2 -> R_A (hJ1 dead)
    __syncthreads();                             // B4
    sgemm(R_A, 64, S2);                          // S2 = x @ h2^T
}

// Direct-output GEMM: out[b, ob+k] = S_l[b,:] . Wt_l[:, dm0+k] + 64*bias.
// 1024 tasks, 1 task/block, 4-way K-split across waves; wave 0 combines.
__global__ __launch_bounds__(256, 4)
void cin_direct(const _Float16* __restrict__ S0v, const _Float16* __restrict__ S1v,
                const _Float16* __restrict__ S2v,
                const _Float16* __restrict__ Wt0, const _Float16* __restrict__ Wt1,
                const _Float16* __restrict__ Wt2,
                const float* __restrict__ bs0, const float* __restrict__ bs1,
                const float* __restrict__ bs2,
                float* __restrict__ out)
{
    __shared__ f32x4 red[3][64];
    const int t = threadIdx.x, lane = t & 63, kh = t >> 6;
    const int lr = lane & 15, q = lane >> 4;
    const int task = blockIdx.x;

    const _Float16 *S, *Wt;
    const float* bias;
    int fan, nch, dm0, ob, idx;
    if (task < 256)      { S = S0v; Wt = Wt0; bias = bs0; fan = 1024; nch = 32; dm0 = 64; ob = 0;   idx = task; }
    else if (task < 512) { S = S1v; Wt = Wt1; bias = bs1; fan = 2048; nch = 64; dm0 = 64; ob = 64;  idx = task - 256; }
    else                 { S = S2v; Wt = Wt2; bias = bs2; fan = 2048; nch = 64; dm0 = 0;  ob = 128; idx = task - 512; }
    const int bt = idx & 63, kt = idx >> 6;
    const int bbase = bt * 16;
    const int hq = nch >> 2, c0 = kh * hq;

    const _Float16* aG = Wt + (size_t)(dm0 + kt * 16 + lr) * 32 + q * 8
                            + (size_t)c0 * 4096;
    const _Float16* bG = S + (size_t)(bbase + lr) * fan + q * 8 + c0 * 32;

    f32x4 acc = {0.0f, 0.0f, 0.0f, 0.0f};
    half8 aA = *(const half8*)(aG);
    half8 bA = *(const half8*)(bG);
    for (int c = 0; c < hq; c += 2) {
        half8 aB = *(const half8*)(aG + (size_t)(c + 1) * 4096);
        half8 bB = *(const half8*)(bG + (c + 1) * 32);
        acc = __builtin_amdgcn_mfma_f32_16x16x32_f16(aA, bA, acc, 0, 0, 0);
        if (c + 2 < hq) {
            aA = *(const half8*)(aG + (size_t)(c + 2) * 4096);
            bA = *(const half8*)(bG + (c + 2) * 32);
        }
        acc = __builtin_amdgcn_mfma_f32_16x16x32_f16(aB, bB, acc, 0, 0, 0);
    }
    if (kh != 0) red[kh - 1][lane] = acc;
    __syncthreads();
    if (kh == 0) {
#pragma unroll
        for (int p = 0; p < 3; ++p) {
            f32x4 o = red[p][lane];
#pragma unroll
            for (int r = 0; r < 4; ++r) acc[r] += o[r];
        }
#pragma unroll
        for (int r = 0; r < 4; ++r) {
            int kl = kt * 16 + q * 4 + r;
            out[(size_t)(bbase + lr) * 256 + ob + kl]
                = acc[r] + 64.0f * bias[dm0 + kl];
        }
    }
}

extern "C" void kernel_launch(void* const* d_in, const int* in_sizes, int n_in,
                              void* d_out, int out_size, void* d_ws, size_t ws_size,
                              hipStream_t stream)
{
    const float* x  = (const float*)d_in[0];
    const float* W0 = (const float*)d_in[1];
    const float* b0 = (const float*)d_in[2];
    const float* W1 = (const float*)d_in[3];
    const float* b1 = (const float*)d_in[4];
    const float* W2 = (const float*)d_in[5];
    const float* b2 = (const float*)d_in[6];
    float* out = (float*)d_out;

    char* ws = (char*)d_ws;
    _Float16* Wt0 = (_Float16*)(ws + 0);           // 256 KB
    _Float16* Wt1 = (_Float16*)(ws + 262144);      // 512 KB
    _Float16* Wt2 = (_Float16*)(ws + 786432);      // 512 KB
    _Float16* S0  = (_Float16*)(ws + 1310720);     // 2 MB  (1024 x 1024 f16)
    _Float16* S1  = (_Float16*)(ws + 3407872);     // 4 MB  (1024 x 2048 f16)
    _Float16* S2  = (_Float16*)(ws + 7602176);     // 4 MB
    (void)in_sizes; (void)n_in; (void)out_size; (void)ws_size;

    hipLaunchKernelGGL(pack_w_all, dim3(160), dim3(256), 0, stream,
                       W0, Wt0, W1, Wt1, W2, Wt2);

    hipLaunchKernelGGL(cin_fused, dim3(1024), dim3(256), 0, stream,
                       x, Wt0, Wt1, b0, b1, S0, S1, S2);

    hipLaunchKernelGGL(cin_direct, dim3(1024), dim3(256), 0, stream,
                       S0, S1, S2, Wt0, Wt1, Wt2, b0, b1, b2, out);
}